// Round 13
// baseline (579.234 us; speedup 1.0000x reference)
//
#include <hip/hip_runtime.h>
#include <hip/hip_bf16.h>
#include <hip/hip_cooperative_groups.h>

namespace cg = cooperative_groups;

#define N_NODES 50000
#define N_EDGE  800000
#define ET      850000          // N_EDGE + N_NODES self loops
#define IN_DIM  256
#define F1      128             // H1*C1
#define NHEAD   4
#define C1      32
#define OUT_C   40
#define NEG     0.2f
#define P_CNT   6272            // ints per partition slice (>= 6250), line-aligned
#define CHUNK   4096            // edges per scan chunk
#define SCAN_BLK 1664           // 8 partitions * 208 chunks
#define GEMM1_BLK 782           // ceil(N_NODES/64)
#define P1_U    2496            // virtual schedule: 1664 build + 832 gemm slots
#define P0_N    89088           // 8*P_CNT + 128*256 + 48*128

typedef __bf16 bf16_8 __attribute__((ext_vector_type(8)));
typedef float  f32x4  __attribute__((ext_vector_type(4)));

#define RL(v, l) __builtin_amdgcn_readlane((v), (l))

static __device__ __forceinline__ ushort f2b(float f) {
    __hip_bfloat16 h = __float2bfloat16(f);
    return *reinterpret_cast<ushort*>(&h);
}
static __device__ __forceinline__ float lrelu(float v) {
    return (v > 0.f) ? v : NEG * v;
}

// BitMode ds_swizzle broadcast: src lane = (lane & 16) | J within each
// 32-lane group. J must be a literal, hence the template.
template<int J>
static __device__ __forceinline__ float bcast16(float p) {
    return __int_as_float(
        __builtin_amdgcn_ds_swizzle(__float_as_int(p), (J << 5) | 16));
}

// ============ ONE cooperative mega-kernel: 5 phases, grid.sync barriers =====
// Round-9 structure with the fatal flaw removed: PLAIN __launch_bounds__(256)
// — the (256,3) min-occupancy pledge capped VGPRs at 64 and spilled the MFMA
// accumulators (FETCH 55->177MB, 2.4x regression). This run isolates the
// inter-dispatch overhead C (>=60us inferred from rounds 5/11 accounting):
// coop removes all 6 dispatch boundaries; if C is dispatch-bound we win it.
__global__ __launch_bounds__(256) void k_mega(
        const float* __restrict__ x, const int* __restrict__ eidx,
        const float* __restrict__ W1,
        const float* __restrict__ a_src1, const float* __restrict__ a_dst1,
        const float* __restrict__ b1,
        const float* __restrict__ W2,
        const float* __restrict__ a_src2, const float* __restrict__ a_dst2,
        const float* __restrict__ b2,
        float* __restrict__ out,
        int* __restrict__ cnt8, ushort* __restrict__ esrc64,
        ushort* __restrict__ W1T, ushort* __restrict__ W2T,
        ushort* __restrict__ h1b, ushort* __restrict__ h1outb,
        ushort* __restrict__ h2b,
        float* __restrict__ als1, float* __restrict__ ald1,
        float* __restrict__ als2, float* __restrict__ ald2) {
    cg::grid_group grid = cg::this_grid();
    __shared__ __align__(16) ushort smem[15232];   // union: gemm1 7680, gemm2 15232
    const int bid = blockIdx.x, t = threadIdx.x;
    const int G = gridDim.x;
    const int w = t >> 6, ln = t & 63;

    // -------- P0: zero cnt8 + weight transpose/convert --------
    for (int i = bid * 256 + t; i < P0_N; i += G * 256) {
        if (i < 8 * P_CNT) cnt8[i] = 0;
        else {
            int j = i - 8 * P_CNT;
            if (j < F1 * IN_DIM) {                    // W1T: n in [0,128), k in [0,256)
                int n = j >> 8, k = j & 255;
                W1T[j] = f2b(W1[k * F1 + n]);
            } else {                                  // W2T: n in [0,48), k in [0,128)
                int j2 = j - F1 * IN_DIM;
                int n = j2 >> 7, k = j2 & 127;
                W2T[j2] = (n < OUT_C) ? f2b(W2[k * OUT_C + n]) : (ushort)0;
            }
        }
    }
    grid.sync();

    // -------- P1: partition-filtered CSR build INTERLEAVED with gemm1 --------
    for (int u = bid; u < P1_U; u += G) {
        if (u % 3 == 2) {
            int gb = u / 3;
            if (gb >= GEMM1_BLK) continue;
            // ---- gemm1 virtual block ----
            ushort* As = smem;               // [64][40]
            ushort* Bs = smem + 2560;        // [128][40]
            int cl = ln & 15, q = ln >> 4;
            int r0 = gb * 64;

            f32x4 acc[8];
#pragma unroll
            for (int i = 0; i < 8; i++) acc[i] = (f32x4){0.f, 0.f, 0.f, 0.f};

            int arow = t >> 2;               // A staging: row, 8 consecutive k
            int akp  = (t & 3) * 8;
            int brow = t >> 1;               // B staging: n, 16 consecutive k
            int bkp  = (t & 1) * 16;
            int agr  = r0 + arow;

            for (int kc = 0; kc < IN_DIM; kc += 32) {
                float4 f0, f1;
                if (agr < N_NODES) {
                    f0 = *(const float4*)&x[(size_t)agr * IN_DIM + kc + akp];
                    f1 = *(const float4*)&x[(size_t)agr * IN_DIM + kc + akp + 4];
                } else {
                    f0 = make_float4(0.f, 0.f, 0.f, 0.f);
                    f1 = f0;
                }
                ushort4 u0 = {f2b(f0.x), f2b(f0.y), f2b(f0.z), f2b(f0.w)};
                ushort4 u1 = {f2b(f1.x), f2b(f1.y), f2b(f1.z), f2b(f1.w)};
                *(ushort4*)&As[arow * 40 + akp]     = u0;
                *(ushort4*)&As[arow * 40 + akp + 4] = u1;

                *(uint4*)&Bs[brow * 40 + bkp]     = *(const uint4*)&W1T[brow * IN_DIM + kc + bkp];
                *(uint4*)&Bs[brow * 40 + bkp + 8] = *(const uint4*)&W1T[brow * IN_DIM + kc + bkp + 8];
                __syncthreads();

                bf16_8 af = *(bf16_8*)&As[(w * 16 + cl) * 40 + q * 8];
#pragma unroll
                for (int ct = 0; ct < 8; ct++) {
                    bf16_8 bfr = *(bf16_8*)&Bs[(ct * 16 + cl) * 40 + q * 8];
                    acc[ct] = __builtin_amdgcn_mfma_f32_16x16x32_bf16(af, bfr, acc[ct], 0, 0, 0);
                }
                __syncthreads();
            }

            float asv[8], adv[8];
#pragma unroll
            for (int ct = 0; ct < 8; ct++) {
                asv[ct] = a_src1[ct * 16 + cl];
                adv[ct] = a_dst1[ct * 16 + cl];
            }

#pragma unroll
            for (int reg = 0; reg < 4; reg++) {
                int grow = r0 + w * 16 + q * 4 + reg;
                bool ok = grow < N_NODES;
                float ps[4] = {0.f, 0.f, 0.f, 0.f};
                float pd[4] = {0.f, 0.f, 0.f, 0.f};
#pragma unroll
                for (int ct = 0; ct < 8; ct++) {
                    float v = acc[ct][reg];
                    if (ok) h1b[(size_t)grow * F1 + ct * 16 + cl] = f2b(v);
                    ps[ct >> 1] += v * asv[ct];
                    pd[ct >> 1] += v * adv[ct];
                }
#pragma unroll
                for (int hh = 0; hh < 4; hh++) {
                    ps[hh] += __shfl_xor(ps[hh], 1); ps[hh] += __shfl_xor(ps[hh], 2);
                    ps[hh] += __shfl_xor(ps[hh], 4); ps[hh] += __shfl_xor(ps[hh], 8);
                    pd[hh] += __shfl_xor(pd[hh], 1); pd[hh] += __shfl_xor(pd[hh], 2);
                    pd[hh] += __shfl_xor(pd[hh], 4); pd[hh] += __shfl_xor(pd[hh], 8);
                }
                if (cl == 0 && ok) {
#pragma unroll
                    for (int hh = 0; hh < 4; hh++) {
                        als1[grow * NHEAD + hh] = ps[hh];
                        ald1[grow * NHEAD + hh] = pd[hh];
                    }
                }
            }
        } else {
            // ---- build virtual block: partition p, chunk c ----
            int vb = u - u / 3;              // in [0, SCAN_BLK)
            int p = vb & 7, c = vb >> 3;
            int* pc = &cnt8[p * P_CNT];
#pragma unroll
            for (int g = 0; g < 4; g++) {
                int e0 = c * CHUNK + g * 1024 + t * 4;
                if (e0 >= ET) continue;              // 4|ET: no straddle
                bool inE = e0 < N_EDGE;              // 4|N_EDGE: no straddle
                int4 dd;
                if (inE) {
                    dd = *(const int4*)&eidx[N_EDGE + e0];
                } else {
                    int d = e0 - N_EDGE;
                    dd = make_int4(d, d + 1, d + 2, d + 3);
                }
                if ((dd.x & 7) == p) {
                    int r = atomicAdd(&pc[dd.x >> 3], 1);
                    if (r < 64) esrc64[(dd.x << 6) + r] = (ushort)(inE ? eidx[e0] : dd.x);
                }
                if ((dd.y & 7) == p) {
                    int r = atomicAdd(&pc[dd.y >> 3], 1);
                    if (r < 64) esrc64[(dd.y << 6) + r] = (ushort)(inE ? eidx[e0 + 1] : dd.y);
                }
                if ((dd.z & 7) == p) {
                    int r = atomicAdd(&pc[dd.z >> 3], 1);
                    if (r < 64) esrc64[(dd.z << 6) + r] = (ushort)(inE ? eidx[e0 + 2] : dd.z);
                }
                if ((dd.w & 7) == p) {
                    int r = atomicAdd(&pc[dd.w >> 3], 1);
                    if (r < 64) esrc64[(dd.w << 6) + r] = (ushort)(inE ? eidx[e0 + 3] : dd.w);
                }
            }
        }
    }
    grid.sync();

    // -------- P2: layer-1 aggregation (round-3 structure, 64-slot rows) -----
    for (int nb = bid; nb * 4 < N_NODES; nb += G) {
        int n = nb * 4 + w;
        if (n >= N_NODES) continue;
        int deg = cnt8[(n & 7) * P_CNT + (n >> 3)];
        if (deg > 64) deg = 64;              // safety clamp (never hit)
        const ushort* row = &esrc64[n << 6];

        int h  = ln >> 4;
        int el = ln & 15;
        float ad = ald1[n * 4 + h];

        float acc0 = 0.f, acc1 = 0.f, ssum = 0.f;
        int base = 0;

#define AGG1_STEP(J) { \
        float pj = bcast16<J>(p); \
        ssum += pj; \
        acc0 = fmaf(pj, __uint_as_float(hv[J] << 16), acc0); \
        acc1 = fmaf(pj, __uint_as_float(hv[J] & 0xffff0000u), acc1); }
#define AGG1_ALL16 \
        AGG1_STEP(0)  AGG1_STEP(1)  AGG1_STEP(2)  AGG1_STEP(3)  \
        AGG1_STEP(4)  AGG1_STEP(5)  AGG1_STEP(6)  AGG1_STEP(7)  \
        AGG1_STEP(8)  AGG1_STEP(9)  AGG1_STEP(10) AGG1_STEP(11) \
        AGG1_STEP(12) AGG1_STEP(13) AGG1_STEP(14) AGG1_STEP(15)

        const uint* h1u = (const uint*)h1b;
        for (; base + 16 <= deg; base += 16) {
            int s_reg = row[base + el];
            float p = __expf(lrelu(als1[s_reg * 4 + h] + ad));
            uint hv[16];
#pragma unroll
            for (int j = 0; j < 16; j++) {
                int sj = RL(s_reg, j);              // SGPR: scalar addr
                hv[j] = h1u[(size_t)sj * 64 + ln];
            }
            AGG1_ALL16
        }

        if (base < deg) {
            int cnt_ = deg - base;
            int s_reg = row[base + (el < cnt_ ? el : 0)];
            float v = lrelu(als1[s_reg * 4 + h] + ad);
            if (el >= cnt_) v = -1e30f;
            float p = __expf(v);                // 0 for inactive slots
            uint hv[16];
#pragma unroll
            for (int j = 0; j < 16; j++) {
                if (j < cnt_) {                 // cnt_ wave-uniform: scalar branch
                    int sj = RL(s_reg, j);
                    hv[j] = h1u[(size_t)sj * 64 + ln];
                } else hv[j] = 0u;
            }
            AGG1_ALL16                          // pj==0 for j>=cnt_
        }

        float inv = 1.f / ssum;
        int c0 = ln * 2;
        float2 bb = *(const float2*)&b1[c0];
        float v0 = acc0 * inv + bb.x;
        float v1 = acc1 * inv + bb.y;
        v0 = (v0 > 0.f) ? v0 : (__expf(v0) - 1.f);   // ELU
        v1 = (v1 > 0.f) ? v1 : (__expf(v1) - 1.f);
        ((uint*)h1outb)[(size_t)n * 64 + ln] = (uint)f2b(v0) | ((uint)f2b(v1) << 16);
    }
    grid.sync();

    // -------- P3: layer-2 GEMM --------
    for (int gb = bid; gb < GEMM1_BLK; gb += G) {
        ushort* As = smem;               // [64][136]
        ushort* Bs = smem + 8704;        // [48][136]
        int cl = ln & 15, q = ln >> 4;
        int r0 = gb * 64;

        __syncthreads();                 // reuse guard across gb iterations
#pragma unroll
        for (int kk = 0; kk < 3; kk++) {
            int j = t + kk * 256;
            int r = j >> 4, s = j & 15;
            *(uint4*)&Bs[r * 136 + s * 8] = *(const uint4*)&W2T[r * F1 + s * 8];
        }
#pragma unroll
        for (int kk = 0; kk < 4; kk++) {
            int j = t + kk * 256;
            int r = j >> 4, s = j & 15;
            int gr = r0 + r;
            uint4 vv = make_uint4(0u, 0u, 0u, 0u);
            if (gr < N_NODES) vv = *(const uint4*)&h1outb[(size_t)gr * F1 + s * 8];
            *(uint4*)&As[r * 136 + s * 8] = vv;
        }
        __syncthreads();

        f32x4 acc[3];
#pragma unroll
        for (int i = 0; i < 3; i++) acc[i] = (f32x4){0.f, 0.f, 0.f, 0.f};
#pragma unroll
        for (int kc = 0; kc < 4; kc++) {
            bf16_8 af = *(bf16_8*)&As[(w * 16 + cl) * 136 + kc * 32 + q * 8];
#pragma unroll
            for (int ct = 0; ct < 3; ct++) {
                bf16_8 bfr = *(bf16_8*)&Bs[(ct * 16 + cl) * 136 + kc * 32 + q * 8];
                acc[ct] = __builtin_amdgcn_mfma_f32_16x16x32_bf16(af, bfr, acc[ct], 0, 0, 0);
            }
        }

        float asv[3], adv[3];
#pragma unroll
        for (int ct = 0; ct < 3; ct++) {
            int col = ct * 16 + cl;
            asv[ct] = (col < OUT_C) ? a_src2[col] : 0.f;
            adv[ct] = (col < OUT_C) ? a_dst2[col] : 0.f;
        }
#pragma unroll
        for (int reg = 0; reg < 4; reg++) {
            int grow = r0 + w * 16 + q * 4 + reg;
            bool ok = grow < N_NODES;
            float ps = 0.f, pd = 0.f;
#pragma unroll
            for (int ct = 0; ct < 3; ct++) {
                float v = acc[ct][reg];
                int col = ct * 16 + cl;
                if (ok && col < OUT_C) h2b[(size_t)grow * OUT_C + col] = f2b(v);
                ps += v * asv[ct];
                pd += v * adv[ct];
            }
            ps += __shfl_xor(ps, 1); ps += __shfl_xor(ps, 2);
            ps += __shfl_xor(ps, 4); ps += __shfl_xor(ps, 8);
            pd += __shfl_xor(pd, 1); pd += __shfl_xor(pd, 2);
            pd += __shfl_xor(pd, 4); pd += __shfl_xor(pd, 8);
            if (cl == 0 && ok) { als2[grow] = ps; ald2[grow] = pd; }
        }
    }
    grid.sync();

    // -------- P4: layer-2 aggregation + log_softmax --------
    for (int nb = bid; nb * 4 < N_NODES; nb += G) {
        int n = nb * 4 + w;
        if (n >= N_NODES) continue;
        int deg = cnt8[(n & 7) * P_CNT + (n >> 3)];
        if (deg > 64) deg = 64;
        const ushort* row = &esrc64[n << 6];
        const uint* h2u = (const uint*)h2b;

        int el = ln & 15;
        int half = ln >> 5;          // 0: even edges, 1: odd edges
        int lc = ln & 31;            // col-pair index
        bool actc = lc < 20;
        float ad = ald2[n];

        float acc0 = 0.f, acc1 = 0.f, ssum = 0.f;
        int base = 0;

        for (; base + 16 <= deg; base += 16) {
            int s_reg = row[base + el];
            float p = __expf(lrelu(als2[s_reg] + ad));
            uint hv[8]; float pv[8];
#pragma unroll
            for (int i = 0; i < 8; i++) {
                int s0 = RL(s_reg, 2 * i), s1 = RL(s_reg, 2 * i + 1);
                int srow = half ? s1 : s0;
                hv[i] = actc ? h2u[(size_t)srow * 20 + lc] : 0u;
                int p0 = RL(__float_as_int(p), 2 * i), p1 = RL(__float_as_int(p), 2 * i + 1);
                pv[i] = __int_as_float(half ? p1 : p0);
            }
#pragma unroll
            for (int i = 0; i < 8; i++) {
                float pj = pv[i];
                ssum += pj;
                acc0 = fmaf(pj, __uint_as_float(hv[i] << 16), acc0);
                acc1 = fmaf(pj, __uint_as_float(hv[i] & 0xffff0000u), acc1);
            }
        }

        if (base < deg) {
            int cnt_ = deg - base;
            int s_reg = row[base + (el < cnt_ ? el : 0)];
            float v = lrelu(als2[s_reg] + ad);
            if (el >= cnt_) v = -1e30f;
            float p = __expf(v);                // 0 for inactive slots
            uint hv[8]; float pv[8];
#pragma unroll
            for (int i = 0; i < 8; i++) {
                int j = 2 * i + half;
                int s0 = RL(s_reg, 2 * i), s1 = RL(s_reg, 2 * i + 1);
                int srow = half ? s1 : s0;
                hv[i] = (actc && j < cnt_) ? h2u[(size_t)srow * 20 + lc] : 0u;
                int p0 = RL(__float_as_int(p), 2 * i), p1 = RL(__float_as_int(p), 2 * i + 1);
                pv[i] = __int_as_float(half ? p1 : p0);   // 0 for j>=cnt_
            }
#pragma unroll
            for (int i = 0; i < 8; i++) {
                float pj = pv[i];
                ssum += pj;
                acc0 = fmaf(pj, __uint_as_float(hv[i] << 16), acc0);
                acc1 = fmaf(pj, __uint_as_float(hv[i] & 0xffff0000u), acc1);
            }
        }

        // combine halves
        acc0 += __shfl_xor(acc0, 32);
        acc1 += __shfl_xor(acc1, 32);
        ssum += __shfl_xor(ssum, 32);

        bool act = ln < 20;
        float inv = 1.f / ssum;
        int c0 = ln * 2;
        float y0 = -1e30f, y1 = -1e30f;
        if (act) {
            y0 = acc0 * inv + b2[c0];
            y1 = acc1 * inv + b2[c0 + 1];
        }
        float mx = fmaxf(y0, y1);
#pragma unroll
        for (int off = 1; off < 64; off <<= 1) mx = fmaxf(mx, __shfl_xor(mx, off));
        float z = act ? (__expf(y0 - mx) + __expf(y1 - mx)) : 0.f;
#pragma unroll
        for (int off = 1; off < 64; off <<= 1) z += __shfl_xor(z, off);
        float lg = logf(z);
        if (act) {
            float2 o = make_float2(y0 - mx - lg, y1 - mx - lg);
            *(float2*)&out[(size_t)n * OUT_C + c0] = o;
        }
    }
}

extern "C" void kernel_launch(void* const* d_in, const int* in_sizes, int n_in,
                              void* d_out, int out_size, void* d_ws, size_t ws_size,
                              hipStream_t stream) {
    const float* x      = (const float*)d_in[0];
    const int*   eidx   = (const int*)d_in[1];
    const float* W1     = (const float*)d_in[2];
    const float* a_src1 = (const float*)d_in[3];
    const float* a_dst1 = (const float*)d_in[4];
    const float* b1     = (const float*)d_in[5];
    const float* W2     = (const float*)d_in[6];
    const float* a_src2 = (const float*)d_in[7];
    const float* a_dst2 = (const float*)d_in[8];
    const float* b2     = (const float*)d_in[9];
    float* out = (float*)d_out;

    // workspace layout
    float* wf    = (float*)d_ws;
    float* als1  = wf;                   // 200,000
    float* ald1  = wf + 200000;          // 200,000
    float* als2  = wf + 400000;          // 50,000
    float* ald2  = wf + 450000;          // 50,000
    ushort* h1b    = (ushort*)(wf + 500000);   // 6,400,000 ushorts
    ushort* h1outb = h1b + 6400000;            // 6,400,000
    ushort* h2b    = h1outb + 6400000;         // 2,000,000
    ushort* W1T    = h2b + 2000000;            // 32,768
    ushort* W2T    = W1T + 32768;              // 6,144
    ushort* esrc64 = W2T + 6144;               // 3,200,000 ushorts (50K x 64)
    int* cnt8    = (int*)(esrc64 + 3200000);   // 8 * P_CNT = 50,176

    static int maxB = 0;
    if (maxB == 0) {
        hipOccupancyMaxActiveBlocksPerMultiprocessor(&maxB, k_mega, 256, 0);
        if (maxB < 1) maxB = 1;
        if (maxB > 8) maxB = 8;
    }
    int grid = maxB * 256;               // 256 CUs, all blocks co-resident

    void* args[] = {
        (void*)&x, (void*)&eidx, (void*)&W1, (void*)&a_src1, (void*)&a_dst1,
        (void*)&b1, (void*)&W2, (void*)&a_src2, (void*)&a_dst2, (void*)&b2,
        (void*)&out, (void*)&cnt8, (void*)&esrc64, (void*)&W1T, (void*)&W2T,
        (void*)&h1b, (void*)&h1outb, (void*)&h2b,
        (void*)&als1, (void*)&ald1, (void*)&als2, (void*)&ald2
    };
    hipLaunchCooperativeKernel((void*)k_mega, dim3(grid), dim3(256),
                               args, 0, stream);
}

// Round 14
// 229.714 us; speedup vs baseline: 2.5215x; 2.5215x over previous
//
#include <hip/hip_runtime.h>
#include <hip/hip_bf16.h>

#define N_NODES 50000
#define N_EDGE  800000
#define ET      850000          // N_EDGE + N_NODES self loops
#define IN_DIM  256
#define F1      128             // H1*C1
#define NHEAD   4
#define C1      32
#define OUT_C   40
#define NEG     0.2f
#define P_CNT   6272            // ints per partition slice (>= 6250), line-aligned
#define CHUNK   2048            // edges per scan chunk (halved: 2x blocks for latency hiding)
#define CPB     416             // chunks per partition: 416*2048 >= ET
#define SCAN_BLK (8 * CPB)      // 3328
#define PREP_BLK 152            // ceil((128*256+48*128)/256)
#define GEMM1_BLK 782           // ceil(N_NODES/64)

typedef __bf16 bf16_8 __attribute__((ext_vector_type(8)));
typedef float  f32x4  __attribute__((ext_vector_type(4)));

#define RL(v, l) __builtin_amdgcn_readlane((v), (l))

static __device__ __forceinline__ ushort f2b(float f) {
    __hip_bfloat16 h = __float2bfloat16(f);
    return *reinterpret_cast<ushort*>(&h);
}
static __device__ __forceinline__ float lrelu(float v) {
    return (v > 0.f) ? v : NEG * v;
}

// BitMode ds_swizzle broadcast: src lane = (lane & 16) | J within each
// 32-lane group. J must be a literal, hence the template.
template<int J>
static __device__ __forceinline__ float bcast16(float p) {
    return __int_as_float(
        __builtin_amdgcn_ds_swizzle(__float_as_int(p), (J << 5) | 16));
}

// ---------------- build: partition-filtered 64-slot CSR + weight prep -------
// Partition p = dst&7. Block b serves partition b&7 and scans chunk b>>3 of
// the dst list, scattering only matching edges -> XCD-local L2 lines, single
// writeback. CHUNK=2048 (was 4096): 3328 blocks saturate the wave pool —
// round 9/10 measured Occupancy 52%, VALUBusy 4.5% = latency-bound with too
// few waves. src gathered lazily inside the match branch.
// NOTE (round 10/12 lessons): no min-occupancy __launch_bounds__ anywhere
// (VGPR cap spills MFMA accs); no coop mega-kernel (2 failures, reg pressure
// + grid-stride structure); build||gemm1 overlap = sum not max (3 failures).
__global__ __launch_bounds__(256) void k_build(
        const int* __restrict__ eidx, int* __restrict__ cnt8,
        ushort* __restrict__ esrc64,
        const float* __restrict__ W1, const float* __restrict__ W2,
        ushort* __restrict__ W1T, ushort* __restrict__ W2T) {
    int bid = blockIdx.x, t = threadIdx.x;
    if (bid < SCAN_BLK) {
        int p = bid & 7, c = bid >> 3;
        int* pc = &cnt8[p * P_CNT];
#pragma unroll
        for (int g = 0; g < CHUNK / 1024; g++) {
            int e0 = c * CHUNK + g * 1024 + t * 4;   // coalesced int4 per wave
            if (e0 >= ET) continue;                  // 4|ET: groups never straddle
            bool inE = e0 < N_EDGE;                  // 4|N_EDGE: no straddle
            int4 dd;
            if (inE) {
                dd = *(const int4*)&eidx[N_EDGE + e0];
            } else {
                int d = e0 - N_EDGE;
                dd = make_int4(d, d + 1, d + 2, d + 3);
            }
            if ((dd.x & 7) == p) {
                int r = atomicAdd(&pc[dd.x >> 3], 1);
                if (r < 64) esrc64[(dd.x << 6) + r] = (ushort)(inE ? eidx[e0] : dd.x);
            }
            if ((dd.y & 7) == p) {
                int r = atomicAdd(&pc[dd.y >> 3], 1);
                if (r < 64) esrc64[(dd.y << 6) + r] = (ushort)(inE ? eidx[e0 + 1] : dd.y);
            }
            if ((dd.z & 7) == p) {
                int r = atomicAdd(&pc[dd.z >> 3], 1);
                if (r < 64) esrc64[(dd.z << 6) + r] = (ushort)(inE ? eidx[e0 + 2] : dd.z);
            }
            if ((dd.w & 7) == p) {
                int r = atomicAdd(&pc[dd.w >> 3], 1);
                if (r < 64) esrc64[(dd.w << 6) + r] = (ushort)(inE ? eidx[e0 + 3] : dd.w);
            }
        }
    } else {
        int j = (bid - SCAN_BLK) * 256 + t;
        if (j < F1 * IN_DIM) {                        // W1T: n in [0,128), k in [0,256)
            int n = j >> 8, k = j & 255;
            W1T[j] = f2b(W1[k * F1 + n]);
        } else if (j - F1 * IN_DIM < 48 * F1) {       // W2T: n in [0,48), k in [0,128)
            int j2 = j - F1 * IN_DIM;
            int n = j2 >> 7, k = j2 & 127;
            W2T[j2] = (n < OUT_C) ? f2b(W2[k * OUT_C + n]) : (ushort)0;
        }
    }
}

// ---------------- layer 1 GEMM via MFMA (+ fused attention logits) ----------
__global__ __launch_bounds__(256) void k_gemm1m(
        const float* __restrict__ x, const ushort* __restrict__ W1T,
        const float* __restrict__ a_src1, const float* __restrict__ a_dst1,
        ushort* __restrict__ h1b, float* __restrict__ als1, float* __restrict__ ald1) {
    __shared__ ushort As[64 * 40];   // [row][k], pad 32->40 to break bank stride
    __shared__ ushort Bs[128 * 40];  // [n][k]
    int t = threadIdx.x;
    int w = t >> 6, lane = t & 63;
    int cl = lane & 15, q = lane >> 4;
    int r0 = blockIdx.x * 64;

    f32x4 acc[8];
#pragma unroll
    for (int i = 0; i < 8; i++) acc[i] = (f32x4){0.f, 0.f, 0.f, 0.f};

    int arow = t >> 2;               // A staging: row, 8 consecutive k
    int akp  = (t & 3) * 8;
    int brow = t >> 1;               // B staging: n, 16 consecutive k
    int bkp  = (t & 1) * 16;
    int agr  = r0 + arow;

    for (int kc = 0; kc < IN_DIM; kc += 32) {
        float4 f0, f1;
        if (agr < N_NODES) {
            f0 = *(const float4*)&x[(size_t)agr * IN_DIM + kc + akp];
            f1 = *(const float4*)&x[(size_t)agr * IN_DIM + kc + akp + 4];
        } else {
            f0 = make_float4(0.f, 0.f, 0.f, 0.f);
            f1 = f0;
        }
        ushort4 u0 = {f2b(f0.x), f2b(f0.y), f2b(f0.z), f2b(f0.w)};
        ushort4 u1 = {f2b(f1.x), f2b(f1.y), f2b(f1.z), f2b(f1.w)};
        *(ushort4*)&As[arow * 40 + akp]     = u0;
        *(ushort4*)&As[arow * 40 + akp + 4] = u1;

        *(uint4*)&Bs[brow * 40 + bkp]     = *(const uint4*)&W1T[brow * IN_DIM + kc + bkp];
        *(uint4*)&Bs[brow * 40 + bkp + 8] = *(const uint4*)&W1T[brow * IN_DIM + kc + bkp + 8];
        __syncthreads();

        bf16_8 af = *(bf16_8*)&As[(w * 16 + cl) * 40 + q * 8];
#pragma unroll
        for (int ct = 0; ct < 8; ct++) {
            bf16_8 bfr = *(bf16_8*)&Bs[(ct * 16 + cl) * 40 + q * 8];
            acc[ct] = __builtin_amdgcn_mfma_f32_16x16x32_bf16(af, bfr, acc[ct], 0, 0, 0);
        }
        __syncthreads();
    }

    float asv[8], adv[8];
#pragma unroll
    for (int ct = 0; ct < 8; ct++) {
        asv[ct] = a_src1[ct * 16 + cl];
        adv[ct] = a_dst1[ct * 16 + cl];
    }

#pragma unroll
    for (int reg = 0; reg < 4; reg++) {
        int grow = r0 + w * 16 + q * 4 + reg;
        bool ok = grow < N_NODES;
        float ps[4] = {0.f, 0.f, 0.f, 0.f};
        float pd[4] = {0.f, 0.f, 0.f, 0.f};
#pragma unroll
        for (int ct = 0; ct < 8; ct++) {
            float v = acc[ct][reg];
            if (ok) h1b[(size_t)grow * F1 + ct * 16 + cl] = f2b(v);
            ps[ct >> 1] += v * asv[ct];
            pd[ct >> 1] += v * adv[ct];
        }
#pragma unroll
        for (int hh = 0; hh < 4; hh++) {
            ps[hh] += __shfl_xor(ps[hh], 1); ps[hh] += __shfl_xor(ps[hh], 2);
            ps[hh] += __shfl_xor(ps[hh], 4); ps[hh] += __shfl_xor(ps[hh], 8);
            pd[hh] += __shfl_xor(pd[hh], 1); pd[hh] += __shfl_xor(pd[hh], 2);
            pd[hh] += __shfl_xor(pd[hh], 4); pd[hh] += __shfl_xor(pd[hh], 8);
        }
        if (cl == 0 && ok) {
#pragma unroll
            for (int hh = 0; hh < 4; hh++) {
                als1[grow * NHEAD + hh] = ps[hh];
                ald1[grow * NHEAD + hh] = pd[hh];
            }
        }
    }
}

// ---------------- layer 1: fused softmax aggregation, one wave per node ------
// Round-3 structure: UNCONDITIONAL 16-gather chunks + zero-masked reduction;
// single guarded tail. Direct 64-slot ushort rows.
__global__ __launch_bounds__(256) void k_agg1w(
        const int* __restrict__ cnt8, const ushort* __restrict__ esrc64,
        const float* __restrict__ als1, const float* __restrict__ ald1,
        const uint* __restrict__ h1u, const float* __restrict__ b1,
        uint* __restrict__ h1outu) {
    int w = threadIdx.x >> 6, ln = threadIdx.x & 63;
    int n = blockIdx.x * 4 + w;
    if (n >= N_NODES) return;
    int deg = cnt8[(n & 7) * P_CNT + (n >> 3)];
    if (deg > 64) deg = 64;                  // safety clamp (never hit)
    const ushort* row = &esrc64[n << 6];

    int h  = ln >> 4;           // head for this lane
    int el = ln & 15;           // edge slot within chunk
    float ad = ald1[n * 4 + h];

    float acc0 = 0.f, acc1 = 0.f, ssum = 0.f;
    int base = 0;

#define AGG1_STEP(J) { \
        float pj = bcast16<J>(p); \
        ssum += pj; \
        acc0 = fmaf(pj, __uint_as_float(hv[J] << 16), acc0); \
        acc1 = fmaf(pj, __uint_as_float(hv[J] & 0xffff0000u), acc1); }
#define AGG1_ALL16 \
        AGG1_STEP(0)  AGG1_STEP(1)  AGG1_STEP(2)  AGG1_STEP(3)  \
        AGG1_STEP(4)  AGG1_STEP(5)  AGG1_STEP(6)  AGG1_STEP(7)  \
        AGG1_STEP(8)  AGG1_STEP(9)  AGG1_STEP(10) AGG1_STEP(11) \
        AGG1_STEP(12) AGG1_STEP(13) AGG1_STEP(14) AGG1_STEP(15)

    for (; base + 16 <= deg; base += 16) {
        int s_reg = row[base + el];
        float p = __expf(lrelu(als1[s_reg * 4 + h] + ad));
        uint hv[16];
#pragma unroll
        for (int j = 0; j < 16; j++) {
            int sj = RL(s_reg, j);              // SGPR: scalar addr
            hv[j] = h1u[(size_t)sj * 64 + ln];
        }
        AGG1_ALL16
    }

    if (base < deg) {
        int cnt_ = deg - base;
        int s_reg = row[base + (el < cnt_ ? el : 0)];
        float v = lrelu(als1[s_reg * 4 + h] + ad);
        if (el >= cnt_) v = -1e30f;
        float p = __expf(v);                // 0 for inactive slots
        uint hv[16];
#pragma unroll
        for (int j = 0; j < 16; j++) {
            if (j < cnt_) {                 // cnt_ is wave-uniform: scalar branch
                int sj = RL(s_reg, j);
                hv[j] = h1u[(size_t)sj * 64 + ln];
            } else hv[j] = 0u;
        }
        AGG1_ALL16                          // pj==0 for j>=cnt_
    }

    float inv = 1.f / ssum;
    int c0 = ln * 2;
    float2 bb = *(const float2*)&b1[c0];
    float v0 = acc0 * inv + bb.x;
    float v1 = acc1 * inv + bb.y;
    v0 = (v0 > 0.f) ? v0 : (__expf(v0) - 1.f);   // ELU
    v1 = (v1 > 0.f) ? v1 : (__expf(v1) - 1.f);
    h1outu[(size_t)n * 64 + ln] = (uint)f2b(v0) | ((uint)f2b(v1) << 16);
}

// ---------------- layer 2 GEMM via MFMA (+ fused logits) ----------------
__global__ __launch_bounds__(256) void k_gemm2m(
        const ushort* __restrict__ h1outb, const ushort* __restrict__ W2T,
        const float* __restrict__ a_src2, const float* __restrict__ a_dst2,
        ushort* __restrict__ h2b, float* __restrict__ als2, float* __restrict__ ald2) {
    __shared__ ushort As[64 * 136];  // [row][k], stride 136 -> 4-bank row skew
    __shared__ ushort Bs[48 * 136];  // [n][k]
    int t = threadIdx.x;
    int w = t >> 6, lane = t & 63;
    int cl = lane & 15, q = lane >> 4;
    int r0 = blockIdx.x * 64;

#pragma unroll
    for (int kk = 0; kk < 3; kk++) {
        int j = t + kk * 256;
        int r = j >> 4, s = j & 15;
        *(uint4*)&Bs[r * 136 + s * 8] = *(const uint4*)&W2T[r * F1 + s * 8];
    }
#pragma unroll
    for (int kk = 0; kk < 4; kk++) {
        int j = t + kk * 256;
        int r = j >> 4, s = j & 15;
        int gr = r0 + r;
        uint4 vv = make_uint4(0u, 0u, 0u, 0u);
        if (gr < N_NODES) vv = *(const uint4*)&h1outb[(size_t)gr * F1 + s * 8];
        *(uint4*)&As[r * 136 + s * 8] = vv;
    }
    __syncthreads();

    f32x4 acc[3];
#pragma unroll
    for (int i = 0; i < 3; i++) acc[i] = (f32x4){0.f, 0.f, 0.f, 0.f};
#pragma unroll
    for (int kc = 0; kc < 4; kc++) {
        bf16_8 af = *(bf16_8*)&As[(w * 16 + cl) * 136 + kc * 32 + q * 8];
#pragma unroll
        for (int ct = 0; ct < 3; ct++) {
            bf16_8 bfr = *(bf16_8*)&Bs[(ct * 16 + cl) * 136 + kc * 32 + q * 8];
            acc[ct] = __builtin_amdgcn_mfma_f32_16x16x32_bf16(af, bfr, acc[ct], 0, 0, 0);
        }
    }

    float asv[3], adv[3];
#pragma unroll
    for (int ct = 0; ct < 3; ct++) {
        int col = ct * 16 + cl;
        asv[ct] = (col < OUT_C) ? a_src2[col] : 0.f;
        adv[ct] = (col < OUT_C) ? a_dst2[col] : 0.f;
    }
#pragma unroll
    for (int reg = 0; reg < 4; reg++) {
        int grow = r0 + w * 16 + q * 4 + reg;
        bool ok = grow < N_NODES;
        float ps = 0.f, pd = 0.f;
#pragma unroll
        for (int ct = 0; ct < 3; ct++) {
            float v = acc[ct][reg];
            int col = ct * 16 + cl;
            if (ok && col < OUT_C) h2b[(size_t)grow * OUT_C + col] = f2b(v);
            ps += v * asv[ct];
            pd += v * adv[ct];
        }
        ps += __shfl_xor(ps, 1); ps += __shfl_xor(ps, 2);
        ps += __shfl_xor(ps, 4); ps += __shfl_xor(ps, 8);
        pd += __shfl_xor(pd, 1); pd += __shfl_xor(pd, 2);
        pd += __shfl_xor(pd, 4); pd += __shfl_xor(pd, 8);
        if (cl == 0 && ok) { als2[grow] = ps; ald2[grow] = pd; }
    }
}

// ---------------- layer 2: fused softmax aggregation + log_softmax ----------
// Round-3 structure, direct 64-slot ushort rows.
__global__ __launch_bounds__(256) void k_agg2w(
        const int* __restrict__ cnt8, const ushort* __restrict__ esrc64,
        const float* __restrict__ als2, const float* __restrict__ ald2,
        const uint* __restrict__ h2u, const float* __restrict__ b2,
        float* __restrict__ out) {
    int w = threadIdx.x >> 6, ln = threadIdx.x & 63;
    int n = blockIdx.x * 4 + w;
    if (n >= N_NODES) return;
    int deg = cnt8[(n & 7) * P_CNT + (n >> 3)];
    if (deg > 64) deg = 64;
    const ushort* row = &esrc64[n << 6];

    int el = ln & 15;
    int half = ln >> 5;          // 0: even edges, 1: odd edges
    int lc = ln & 31;            // col-pair index
    bool actc = lc < 20;
    float ad = ald2[n];

    float acc0 = 0.f, acc1 = 0.f, ssum = 0.f;
    int base = 0;

    for (; base + 16 <= deg; base += 16) {
        int s_reg = row[base + el];
        float p = __expf(lrelu(als2[s_reg] + ad));
        uint hv[8]; float pv[8];
#pragma unroll
        for (int i = 0; i < 8; i++) {
            int s0 = RL(s_reg, 2 * i), s1 = RL(s_reg, 2 * i + 1);
            int srow = half ? s1 : s0;
            hv[i] = actc ? h2u[(size_t)srow * 20 + lc] : 0u;
            int p0 = RL(__float_as_int(p), 2 * i), p1 = RL(__float_as_int(p), 2 * i + 1);
            pv[i] = __int_as_float(half ? p1 : p0);
        }
#pragma unroll
        for (int i = 0; i < 8; i++) {
            float pj = pv[i];
            ssum += pj;
            acc0 = fmaf(pj, __uint_as_float(hv[i] << 16), acc0);
            acc1 = fmaf(pj, __uint_as_float(hv[i] & 0xffff0000u), acc1);
        }
    }

    if (base < deg) {
        int cnt_ = deg - base;
        int s_reg = row[base + (el < cnt_ ? el : 0)];
        float v = lrelu(als2[s_reg] + ad);
        if (el >= cnt_) v = -1e30f;
        float p = __expf(v);                // 0 for inactive slots
        uint hv[8]; float pv[8];
#pragma unroll
        for (int i = 0; i < 8; i++) {
            int j = 2 * i + half;           // per-lane (parity differs by half)
            int s0 = RL(s_reg, 2 * i), s1 = RL(s_reg, 2 * i + 1);
            int srow = half ? s1 : s0;
            hv[i] = (actc && j < cnt_) ? h2u[(size_t)srow * 20 + lc] : 0u;
            int p0 = RL(__float_as_int(p), 2 * i), p1 = RL(__float_as_int(p), 2 * i + 1);
            pv[i] = __int_as_float(half ? p1 : p0);   // 0 for j>=cnt_
        }
#pragma unroll
        for (int i = 0; i < 8; i++) {
            float pj = pv[i];
            ssum += pj;
            acc0 = fmaf(pj, __uint_as_float(hv[i] << 16), acc0);
            acc1 = fmaf(pj, __uint_as_float(hv[i] & 0xffff0000u), acc1);
        }
    }

    // combine halves
    acc0 += __shfl_xor(acc0, 32);
    acc1 += __shfl_xor(acc1, 32);
    ssum += __shfl_xor(ssum, 32);

    bool act = ln < 20;
    float inv = 1.f / ssum;
    int c0 = ln * 2;
    float y0 = -1e30f, y1 = -1e30f;
    if (act) {
        y0 = acc0 * inv + b2[c0];
        y1 = acc1 * inv + b2[c0 + 1];
    }
    float mx = fmaxf(y0, y1);
#pragma unroll
    for (int off = 1; off < 64; off <<= 1) mx = fmaxf(mx, __shfl_xor(mx, off));
    float z = act ? (__expf(y0 - mx) + __expf(y1 - mx)) : 0.f;
#pragma unroll
    for (int off = 1; off < 64; off <<= 1) z += __shfl_xor(z, off);
    float lg = logf(z);
    if (act) {
        float2 o = make_float2(y0 - mx - lg, y1 - mx - lg);
        *(float2*)&out[(size_t)n * OUT_C + c0] = o;
    }
}

extern "C" void kernel_launch(void* const* d_in, const int* in_sizes, int n_in,
                              void* d_out, int out_size, void* d_ws, size_t ws_size,
                              hipStream_t stream) {
    const float* x      = (const float*)d_in[0];
    const int*   eidx   = (const int*)d_in[1];
    const float* W1     = (const float*)d_in[2];
    const float* a_src1 = (const float*)d_in[3];
    const float* a_dst1 = (const float*)d_in[4];
    const float* b1     = (const float*)d_in[5];
    const float* W2     = (const float*)d_in[6];
    const float* a_src2 = (const float*)d_in[7];
    const float* a_dst2 = (const float*)d_in[8];
    const float* b2     = (const float*)d_in[9];
    float* out = (float*)d_out;

    // workspace layout
    float* wf    = (float*)d_ws;
    float* als1  = wf;                   // 200,000
    float* ald1  = wf + 200000;          // 200,000
    float* als2  = wf + 400000;          // 50,000
    float* ald2  = wf + 450000;          // 50,000
    ushort* h1b    = (ushort*)(wf + 500000);   // 6,400,000 ushorts
    ushort* h1outb = h1b + 6400000;            // 6,400,000
    ushort* h2b    = h1outb + 6400000;         // 2,000,000
    ushort* W1T    = h2b + 2000000;            // 32,768
    ushort* W2T    = W1T + 32768;              // 6,144
    ushort* esrc64 = W2T + 6144;               // 3,200,000 ushorts (50K x 64)
    int* cnt8    = (int*)(esrc64 + 3200000);   // 8 * P_CNT = 50,176

    // graph build: partition-filtered one-pass scatter (XCD-local lines)
    hipMemsetAsync(cnt8, 0, 8 * P_CNT * sizeof(int), stream);
    k_build<<<SCAN_BLK + PREP_BLK, 256, 0, stream>>>(eidx, cnt8, esrc64,
                                                     W1, W2, W1T, W2T);

    // layer 1
    k_gemm1m<<<GEMM1_BLK, 256, 0, stream>>>(x, W1T, a_src1, a_dst1, h1b, als1, ald1);
    k_agg1w<<<(N_NODES + 3) / 4, 256, 0, stream>>>(cnt8, esrc64, als1, ald1,
                                                   (const uint*)h1b, b1, (uint*)h1outb);

    // layer 2
    k_gemm2m<<<GEMM1_BLK, 256, 0, stream>>>(h1outb, W2T, a_src2, a_dst2,
                                            h2b, als2, ald2);
    k_agg2w<<<(N_NODES + 3) / 4, 256, 0, stream>>>(cnt8, esrc64, als2, ald2,
                                                   (const uint*)h2b, b2, out);
}

// Round 15
// 226.087 us; speedup vs baseline: 2.5620x; 1.0160x over previous
//
#include <hip/hip_runtime.h>
#include <hip/hip_bf16.h>

#define N_NODES 50000
#define N_EDGE  800000
#define ET      850000          // N_EDGE + N_NODES self loops
#define IN_DIM  256
#define F1      128             // H1*C1
#define NHEAD   4
#define C1      32
#define OUT_C   40
#define NEG     0.2f
#define P_CNT   6272            // ints per partition slice (>= 6250), line-aligned
#define CHUNK   4096            // edges per scan chunk
#define CPB     208             // chunks per partition
#define SCAN_BLK (8 * CPB)      // 1664
#define PREP_BLK 152            // ceil((128*256+48*128)/256)
#define GEMM1_BLK 782           // ceil(N_NODES/64)
#define BSTRIDE 264             // 256 + 8 pad: LDS row stride (2-way bank alias = free)

typedef __bf16 bf16_8 __attribute__((ext_vector_type(8)));
typedef float  f32x4  __attribute__((ext_vector_type(4)));

#define RL(v, l) __builtin_amdgcn_readlane((v), (l))

static __device__ __forceinline__ ushort f2b(float f) {
    __hip_bfloat16 h = __float2bfloat16(f);
    return *reinterpret_cast<ushort*>(&h);
}
static __device__ __forceinline__ float lrelu(float v) {
    return (v > 0.f) ? v : NEG * v;
}

// BitMode ds_swizzle broadcast: src lane = (lane & 16) | J within each
// 32-lane group. J must be a literal, hence the template.
template<int J>
static __device__ __forceinline__ float bcast16(float p) {
    return __int_as_float(
        __builtin_amdgcn_ds_swizzle(__float_as_int(p), (J << 5) | 16));
}

// ---------------- build: partition-filtered 64-slot CSR + weight prep -------
// Pinned at ~42us (atomic-chain floor: partitioning 52->42, then read-halving,
// ushort, 2x-occupancy all null). Do not touch further.
__global__ __launch_bounds__(256) void k_build(
        const int* __restrict__ eidx, int* __restrict__ cnt8,
        ushort* __restrict__ esrc64,
        const float* __restrict__ W1, const float* __restrict__ W2,
        ushort* __restrict__ W1T, ushort* __restrict__ W2T) {
    int bid = blockIdx.x, t = threadIdx.x;
    if (bid < SCAN_BLK) {
        int p = bid & 7, c = bid >> 3;
        int* pc = &cnt8[p * P_CNT];
#pragma unroll
        for (int g = 0; g < 4; g++) {
            int e0 = c * CHUNK + g * 1024 + t * 4;   // coalesced int4 per wave
            if (e0 >= ET) continue;                  // 4|ET: groups never straddle
            bool inE = e0 < N_EDGE;                  // 4|N_EDGE: no straddle
            int4 dd;
            if (inE) {
                dd = *(const int4*)&eidx[N_EDGE + e0];
            } else {
                int d = e0 - N_EDGE;
                dd = make_int4(d, d + 1, d + 2, d + 3);
            }
            if ((dd.x & 7) == p) {
                int r = atomicAdd(&pc[dd.x >> 3], 1);
                if (r < 64) esrc64[(dd.x << 6) + r] = (ushort)(inE ? eidx[e0] : dd.x);
            }
            if ((dd.y & 7) == p) {
                int r = atomicAdd(&pc[dd.y >> 3], 1);
                if (r < 64) esrc64[(dd.y << 6) + r] = (ushort)(inE ? eidx[e0 + 1] : dd.y);
            }
            if ((dd.z & 7) == p) {
                int r = atomicAdd(&pc[dd.z >> 3], 1);
                if (r < 64) esrc64[(dd.z << 6) + r] = (ushort)(inE ? eidx[e0 + 2] : dd.z);
            }
            if ((dd.w & 7) == p) {
                int r = atomicAdd(&pc[dd.w >> 3], 1);
                if (r < 64) esrc64[(dd.w << 6) + r] = (ushort)(inE ? eidx[e0 + 3] : dd.w);
            }
        }
    } else {
        int j = (bid - SCAN_BLK) * 256 + t;
        if (j < F1 * IN_DIM) {                        // W1T: n in [0,128), k in [0,256)
            int n = j >> 8, k = j & 255;
            W1T[j] = f2b(W1[k * F1 + n]);
        } else if (j - F1 * IN_DIM < 48 * F1) {       // W2T: n in [0,48), k in [0,128)
            int j2 = j - F1 * IN_DIM;
            int n = j2 >> 7, k = j2 & 127;
            W2T[j2] = (n < OUT_C) ? f2b(W2[k * OUT_C + n]) : (ushort)0;
        }
    }
}

// ---------------- layer 1 GEMM: B fully LDS-resident, ZERO-barrier K-loop ---
// W1T (64KB) fits LDS entirely -> load once (1 barrier total). Each wave's
// A-fragment is read DIRECTLY from global x (lane (cl,q): 32B, q-lanes form
// contiguous 128B segments per row; x streamed exactly once). Removes the
// 16 per-block barriers that pinned the old version at 2.1 TB/s.
__global__ __launch_bounds__(256) void k_gemm1m(
        const float* __restrict__ x, const ushort* __restrict__ W1T,
        const float* __restrict__ a_src1, const float* __restrict__ a_dst1,
        ushort* __restrict__ h1b, float* __restrict__ als1, float* __restrict__ ald1) {
    __shared__ ushort Bs[128 * BSTRIDE];   // 67.6 KB
    int t = threadIdx.x;
    int w = t >> 6, lane = t & 63;
    int cl = lane & 15, q = lane >> 4;
    int r0 = blockIdx.x * 64;

    // stage ALL of B once: 4096 uint4s, 16 per thread
#pragma unroll
    for (int kk = 0; kk < 16; kk++) {
        int j = t + kk * 256;
        int r = j >> 5, s = j & 31;            // 32 uint4 per 256-ushort row
        *(uint4*)&Bs[r * BSTRIDE + s * 8] = *(const uint4*)&W1T[r * IN_DIM + s * 8];
    }
    __syncthreads();                            // the only barrier

    f32x4 acc[8];
#pragma unroll
    for (int i = 0; i < 8; i++) acc[i] = (f32x4){0.f, 0.f, 0.f, 0.f};

    int arow = r0 + w * 16 + cl;
    bool okr = arow < N_NODES;
    const float* xr = &x[(size_t)(okr ? arow : 0) * IN_DIM];

    for (int kc = 0; kc < IN_DIM; kc += 32) {
        float4 f0 = make_float4(0.f, 0.f, 0.f, 0.f), f1 = f0;
        if (okr) {
            f0 = *(const float4*)&xr[kc + q * 8];
            f1 = *(const float4*)&xr[kc + q * 8 + 4];
        }
        ushort au[8] = {f2b(f0.x), f2b(f0.y), f2b(f0.z), f2b(f0.w),
                        f2b(f1.x), f2b(f1.y), f2b(f1.z), f2b(f1.w)};
        bf16_8 af = *(bf16_8*)au;
#pragma unroll
        for (int ct = 0; ct < 8; ct++) {
            bf16_8 bfr = *(bf16_8*)&Bs[(ct * 16 + cl) * BSTRIDE + kc + q * 8];
            acc[ct] = __builtin_amdgcn_mfma_f32_16x16x32_bf16(af, bfr, acc[ct], 0, 0, 0);
        }
    }

    float asv[8], adv[8];
#pragma unroll
    for (int ct = 0; ct < 8; ct++) {
        asv[ct] = a_src1[ct * 16 + cl];
        adv[ct] = a_dst1[ct * 16 + cl];
    }

#pragma unroll
    for (int reg = 0; reg < 4; reg++) {
        int grow = r0 + w * 16 + q * 4 + reg;
        bool ok = grow < N_NODES;
        float ps[4] = {0.f, 0.f, 0.f, 0.f};
        float pd[4] = {0.f, 0.f, 0.f, 0.f};
#pragma unroll
        for (int ct = 0; ct < 8; ct++) {
            float v = acc[ct][reg];
            if (ok) h1b[(size_t)grow * F1 + ct * 16 + cl] = f2b(v);
            ps[ct >> 1] += v * asv[ct];
            pd[ct >> 1] += v * adv[ct];
        }
#pragma unroll
        for (int hh = 0; hh < 4; hh++) {
            ps[hh] += __shfl_xor(ps[hh], 1); ps[hh] += __shfl_xor(ps[hh], 2);
            ps[hh] += __shfl_xor(ps[hh], 4); ps[hh] += __shfl_xor(ps[hh], 8);
            pd[hh] += __shfl_xor(pd[hh], 1); pd[hh] += __shfl_xor(pd[hh], 2);
            pd[hh] += __shfl_xor(pd[hh], 4); pd[hh] += __shfl_xor(pd[hh], 8);
        }
        if (cl == 0 && ok) {
#pragma unroll
            for (int hh = 0; hh < 4; hh++) {
                als1[grow * NHEAD + hh] = ps[hh];
                ald1[grow * NHEAD + hh] = pd[hh];
            }
        }
    }
}

// ---------------- layer 1: fused softmax aggregation, one wave per node ------
__global__ __launch_bounds__(256) void k_agg1w(
        const int* __restrict__ cnt8, const ushort* __restrict__ esrc64,
        const float* __restrict__ als1, const float* __restrict__ ald1,
        const uint* __restrict__ h1u, const float* __restrict__ b1,
        uint* __restrict__ h1outu) {
    int w = threadIdx.x >> 6, ln = threadIdx.x & 63;
    int n = blockIdx.x * 4 + w;
    if (n >= N_NODES) return;
    int deg = cnt8[(n & 7) * P_CNT + (n >> 3)];
    if (deg > 64) deg = 64;                  // safety clamp (never hit)
    const ushort* row = &esrc64[n << 6];

    int h  = ln >> 4;           // head for this lane
    int el = ln & 15;           // edge slot within chunk
    float ad = ald1[n * 4 + h];

    float acc0 = 0.f, acc1 = 0.f, ssum = 0.f;
    int base = 0;

#define AGG1_STEP(J) { \
        float pj = bcast16<J>(p); \
        ssum += pj; \
        acc0 = fmaf(pj, __uint_as_float(hv[J] << 16), acc0); \
        acc1 = fmaf(pj, __uint_as_float(hv[J] & 0xffff0000u), acc1); }
#define AGG1_ALL16 \
        AGG1_STEP(0)  AGG1_STEP(1)  AGG1_STEP(2)  AGG1_STEP(3)  \
        AGG1_STEP(4)  AGG1_STEP(5)  AGG1_STEP(6)  AGG1_STEP(7)  \
        AGG1_STEP(8)  AGG1_STEP(9)  AGG1_STEP(10) AGG1_STEP(11) \
        AGG1_STEP(12) AGG1_STEP(13) AGG1_STEP(14) AGG1_STEP(15)

    for (; base + 16 <= deg; base += 16) {
        int s_reg = row[base + el];
        float p = __expf(lrelu(als1[s_reg * 4 + h] + ad));
        uint hv[16];
#pragma unroll
        for (int j = 0; j < 16; j++) {
            int sj = RL(s_reg, j);              // SGPR: scalar addr
            hv[j] = h1u[(size_t)sj * 64 + ln];
        }
        AGG1_ALL16
    }

    if (base < deg) {
        int cnt_ = deg - base;
        int s_reg = row[base + (el < cnt_ ? el : 0)];
        float v = lrelu(als1[s_reg * 4 + h] + ad);
        if (el >= cnt_) v = -1e30f;
        float p = __expf(v);                // 0 for inactive slots
        uint hv[16];
#pragma unroll
        for (int j = 0; j < 16; j++) {
            if (j < cnt_) {                 // cnt_ is wave-uniform: scalar branch
                int sj = RL(s_reg, j);
                hv[j] = h1u[(size_t)sj * 64 + ln];
            } else hv[j] = 0u;
        }
        AGG1_ALL16                          // pj==0 for j>=cnt_
    }

    float inv = 1.f / ssum;
    int c0 = ln * 2;
    float2 bb = *(const float2*)&b1[c0];
    float v0 = acc0 * inv + bb.x;
    float v1 = acc1 * inv + bb.y;
    v0 = (v0 > 0.f) ? v0 : (__expf(v0) - 1.f);   // ELU
    v1 = (v1 > 0.f) ? v1 : (__expf(v1) - 1.f);
    h1outu[(size_t)n * 64 + ln] = (uint)f2b(v0) | ((uint)f2b(v1) << 16);
}

// ---------------- layer 2 GEMM: B LDS-resident, A direct-from-global --------
// As staging removed entirely (A-frags are native bf16 16B loads from
// h1outb). LDS 30.4 -> 13.1 KB; single barrier.
__global__ __launch_bounds__(256) void k_gemm2m(
        const ushort* __restrict__ h1outb, const ushort* __restrict__ W2T,
        const float* __restrict__ a_src2, const float* __restrict__ a_dst2,
        ushort* __restrict__ h2b, float* __restrict__ als2, float* __restrict__ ald2) {
    __shared__ ushort Bs[48 * 136];  // [n][k], stride 136 -> 2-way alias (free)
    int t = threadIdx.x;
    int w = t >> 6, lane = t & 63;
    int cl = lane & 15, q = lane >> 4;
    int r0 = blockIdx.x * 64;

#pragma unroll
    for (int kk = 0; kk < 3; kk++) {
        int j = t + kk * 256;
        int r = j >> 4, s = j & 15;
        *(uint4*)&Bs[r * 136 + s * 8] = *(const uint4*)&W2T[r * F1 + s * 8];
    }
    __syncthreads();

    int arow = r0 + w * 16 + cl;
    bool okr = arow < N_NODES;
    const ushort* ar = &h1outb[(size_t)(okr ? arow : 0) * F1];

    f32x4 acc[3];
#pragma unroll
    for (int i = 0; i < 3; i++) acc[i] = (f32x4){0.f, 0.f, 0.f, 0.f};
#pragma unroll
    for (int kc = 0; kc < 4; kc++) {
        bf16_8 af;
        if (okr) af = *(const bf16_8*)&ar[kc * 32 + q * 8];
        else {
            ushort zz[8] = {0, 0, 0, 0, 0, 0, 0, 0};
            af = *(bf16_8*)zz;
        }
#pragma unroll
        for (int ct = 0; ct < 3; ct++) {
            bf16_8 bfr = *(bf16_8*)&Bs[(ct * 16 + cl) * 136 + kc * 32 + q * 8];
            acc[ct] = __builtin_amdgcn_mfma_f32_16x16x32_bf16(af, bfr, acc[ct], 0, 0, 0);
        }
    }

    float asv[3], adv[3];
#pragma unroll
    for (int ct = 0; ct < 3; ct++) {
        int col = ct * 16 + cl;
        asv[ct] = (col < OUT_C) ? a_src2[col] : 0.f;
        adv[ct] = (col < OUT_C) ? a_dst2[col] : 0.f;
    }
#pragma unroll
    for (int reg = 0; reg < 4; reg++) {
        int grow = r0 + w * 16 + q * 4 + reg;
        bool ok = grow < N_NODES;
        float ps = 0.f, pd = 0.f;
#pragma unroll
        for (int ct = 0; ct < 3; ct++) {
            float v = acc[ct][reg];
            int col = ct * 16 + cl;
            if (ok && col < OUT_C) h2b[(size_t)grow * OUT_C + col] = f2b(v);
            ps += v * asv[ct];
            pd += v * adv[ct];
        }
        ps += __shfl_xor(ps, 1); ps += __shfl_xor(ps, 2);
        ps += __shfl_xor(ps, 4); ps += __shfl_xor(ps, 8);
        pd += __shfl_xor(pd, 1); pd += __shfl_xor(pd, 2);
        pd += __shfl_xor(pd, 4); pd += __shfl_xor(pd, 8);
        if (cl == 0 && ok) { als2[grow] = ps; ald2[grow] = pd; }
    }
}

// ---------------- layer 2: fused softmax aggregation + log_softmax ----------
__global__ __launch_bounds__(256) void k_agg2w(
        const int* __restrict__ cnt8, const ushort* __restrict__ esrc64,
        const float* __restrict__ als2, const float* __restrict__ ald2,
        const uint* __restrict__ h2u, const float* __restrict__ b2,
        float* __restrict__ out) {
    int w = threadIdx.x >> 6, ln = threadIdx.x & 63;
    int n = blockIdx.x * 4 + w;
    if (n >= N_NODES) return;
    int deg = cnt8[(n & 7) * P_CNT + (n >> 3)];
    if (deg > 64) deg = 64;
    const ushort* row = &esrc64[n << 6];

    int el = ln & 15;
    int half = ln >> 5;          // 0: even edges, 1: odd edges
    int lc = ln & 31;            // col-pair index
    bool actc = lc < 20;
    float ad = ald2[n];

    float acc0 = 0.f, acc1 = 0.f, ssum = 0.f;
    int base = 0;

    for (; base + 16 <= deg; base += 16) {
        int s_reg = row[base + el];
        float p = __expf(lrelu(als2[s_reg] + ad));
        uint hv[8]; float pv[8];
#pragma unroll
        for (int i = 0; i < 8; i++) {
            int s0 = RL(s_reg, 2 * i), s1 = RL(s_reg, 2 * i + 1);
            int srow = half ? s1 : s0;
            hv[i] = actc ? h2u[(size_t)srow * 20 + lc] : 0u;
            int p0 = RL(__float_as_int(p), 2 * i), p1 = RL(__float_as_int(p), 2 * i + 1);
            pv[i] = __int_as_float(half ? p1 : p0);
        }
#pragma unroll
        for (int i = 0; i < 8; i++) {
            float pj = pv[i];
            ssum += pj;
            acc0 = fmaf(pj, __uint_as_float(hv[i] << 16), acc0);
            acc1 = fmaf(pj, __uint_as_float(hv[i] & 0xffff0000u), acc1);
        }
    }

    if (base < deg) {
        int cnt_ = deg - base;
        int s_reg = row[base + (el < cnt_ ? el : 0)];
        float v = lrelu(als2[s_reg] + ad);
        if (el >= cnt_) v = -1e30f;
        float p = __expf(v);                // 0 for inactive slots
        uint hv[8]; float pv[8];
#pragma unroll
        for (int i = 0; i < 8; i++) {
            int j = 2 * i + half;           // per-lane (parity differs by half)
            int s0 = RL(s_reg, 2 * i), s1 = RL(s_reg, 2 * i + 1);
            int srow = half ? s1 : s0;
            hv[i] = (actc && j < cnt_) ? h2u[(size_t)srow * 20 + lc] : 0u;
            int p0 = RL(__float_as_int(p), 2 * i), p1 = RL(__float_as_int(p), 2 * i + 1);
            pv[i] = __int_as_float(half ? p1 : p0);   // 0 for j>=cnt_
        }
#pragma unroll
        for (int i = 0; i < 8; i++) {
            float pj = pv[i];
            ssum += pj;
            acc0 = fmaf(pj, __uint_as_float(hv[i] << 16), acc0);
            acc1 = fmaf(pj, __uint_as_float(hv[i] & 0xffff0000u), acc1);
        }
    }

    // combine halves
    acc0 += __shfl_xor(acc0, 32);
    acc1 += __shfl_xor(acc1, 32);
    ssum += __shfl_xor(ssum, 32);

    bool act = ln < 20;
    float inv = 1.f / ssum;
    int c0 = ln * 2;
    float y0 = -1e30f, y1 = -1e30f;
    if (act) {
        y0 = acc0 * inv + b2[c0];
        y1 = acc1 * inv + b2[c0 + 1];
    }
    float mx = fmaxf(y0, y1);
#pragma unroll
    for (int off = 1; off < 64; off <<= 1) mx = fmaxf(mx, __shfl_xor(mx, off));
    float z = act ? (__expf(y0 - mx) + __expf(y1 - mx)) : 0.f;
#pragma unroll
    for (int off = 1; off < 64; off <<= 1) z += __shfl_xor(z, off);
    float lg = logf(z);
    if (act) {
        float2 o = make_float2(y0 - mx - lg, y1 - mx - lg);
        *(float2*)&out[(size_t)n * OUT_C + c0] = o;
    }
}

extern "C" void kernel_launch(void* const* d_in, const int* in_sizes, int n_in,
                              void* d_out, int out_size, void* d_ws, size_t ws_size,
                              hipStream_t stream) {
    const float* x      = (const float*)d_in[0];
    const int*   eidx   = (const int*)d_in[1];
    const float* W1     = (const float*)d_in[2];
    const float* a_src1 = (const float*)d_in[3];
    const float* a_dst1 = (const float*)d_in[4];
    const float* b1     = (const float*)d_in[5];
    const float* W2     = (const float*)d_in[6];
    const float* a_src2 = (const float*)d_in[7];
    const float* a_dst2 = (const float*)d_in[8];
    const float* b2     = (const float*)d_in[9];
    float* out = (float*)d_out;

    // workspace layout
    float* wf    = (float*)d_ws;
    float* als1  = wf;                   // 200,000
    float* ald1  = wf + 200000;          // 200,000
    float* als2  = wf + 400000;          // 50,000
    float* ald2  = wf + 450000;          // 50,000
    ushort* h1b    = (ushort*)(wf + 500000);   // 6,400,000 ushorts
    ushort* h1outb = h1b + 6400000;            // 6,400,000
    ushort* h2b    = h1outb + 6400000;         // 2,000,000
    ushort* W1T    = h2b + 2000000;            // 32,768
    ushort* W2T    = W1T + 32768;              // 6,144
    ushort* esrc64 = W2T + 6144;               // 3,200,000 ushorts (50K x 64)
    int* cnt8    = (int*)(esrc64 + 3200000);   // 8 * P_CNT = 50,176

    // graph build: partition-filtered one-pass scatter (XCD-local lines)
    hipMemsetAsync(cnt8, 0, 8 * P_CNT * sizeof(int), stream);
    k_build<<<SCAN_BLK + PREP_BLK, 256, 0, stream>>>(eidx, cnt8, esrc64,
                                                     W1, W2, W1T, W2T);

    // layer 1
    k_gemm1m<<<GEMM1_BLK, 256, 0, stream>>>(x, W1T, a_src1, a_dst1, h1b, als1, ald1);
    k_agg1w<<<(N_NODES + 3) / 4, 256, 0, stream>>>(cnt8, esrc64, als1, ald1,
                                                   (const uint*)h1b, b1, (uint*)h1outb);

    // layer 2
    k_gemm2m<<<GEMM1_BLK, 256, 0, stream>>>(h1outb, W2T, a_src2, a_dst2,
                                            h2b, als2, ald2);
    k_agg2w<<<(N_NODES + 3) / 4, 256, 0, stream>>>(cnt8, esrc64, als2, ald2,
                                                   (const uint*)h2b, b2, out);
}